// Round 6
// baseline (370.765 us; speedup 1.0000x reference)
//
#include <hip/hip_runtime.h>
#include <hip/hip_bf16.h>
#include <hip/hip_cooperative_groups.h>

namespace cg = cooperative_groups;

#define N_NODES    100000
#define N_EDGES    1200000
#define NUM_GRAPHS 128
#define IN_DIM     5
#define HIDDEN     64
#define M_TILES    (N_NODES / 16)   // 6250 (exact)
#define NI4        (N_EDGES / 4)    // 300000 int4 groups

#define CB    391                   // coarse buckets of 256 nodes: ceil(N/256)
#define CBLK  256                   // partition blocks
#define EPB   ((NI4 + CBLK - 1) / CBLK)   // 1172 int4-groups per block

typedef __attribute__((ext_vector_type(8))) short short8;   // 8 bf16 (4 VGPRs)
typedef __attribute__((ext_vector_type(4))) float f32x4;
typedef __attribute__((ext_vector_type(2))) float f32x2;

#if defined(__has_builtin)
#if __has_builtin(__builtin_amdgcn_cvt_pk_f32_fp8)
#define HAS_HWF8 1
#endif
#endif

// fp32 -> bf16 bits (RNE)
__device__ __forceinline__ unsigned short f2bs(float f) {
    union { float f; unsigned u; } v; v.f = f;
    return (unsigned short)((v.u + 0x7FFFu + ((v.u >> 16) & 1u)) >> 16);
}
// bf16 bits -> fp32
__device__ __forceinline__ float bs2f(unsigned short s) {
    union { unsigned u; float f; } v; v.u = ((unsigned)s) << 16;
    return v.f;
}
__device__ __forceinline__ float blo(unsigned p) { return bs2f((unsigned short)(p & 0xffff)); }
__device__ __forceinline__ float bhi(unsigned p) { return bs2f((unsigned short)(p >> 16)); }
__device__ __forceinline__ unsigned pack2(float a, float b) {
    return ((unsigned)f2bs(b) << 16) | (unsigned)f2bs(a);
}

// fp32 (>=0) -> fp8 e4m3 bits (OCP), RNE, denorm-exact (magic-multiply trick)
__device__ __forceinline__ unsigned char f2f8(float f) {
    union { float f; unsigned u; } v; v.f = f * 0x1p-120f;
    unsigned u = v.u + 0x7FFFFu + ((v.u >> 20) & 1u);
    return (unsigned char)(u >> 20);
}
// fp8 e4m3 bits -> fp32 (exact inverse)
__device__ __forceinline__ float f82f(unsigned b) {
    union { unsigned u; float f; } v; v.u = (b & 0x7Fu) << 20;
    return v.f * 0x1p120f;
}

// accumulate 4 fp8 bytes of r into a (HW decode when available; bit-identical)
__device__ __forceinline__ void acc8(float4& a, unsigned r) {
#ifdef HAS_HWF8
    f32x2 lo = __builtin_amdgcn_cvt_pk_f32_fp8((int)r, false);
    f32x2 hi = __builtin_amdgcn_cvt_pk_f32_fp8((int)r, true);
    a.x += lo[0]; a.y += lo[1]; a.z += hi[0]; a.w += hi[1];
#else
    a.x += f82f(r); a.y += f82f(r >> 8); a.z += f82f(r >> 16); a.w += f82f(r >> 24);
#endif
}

// ==================== CSR build ============================================
// part entries are PACKED 4B: src (bits 0..16) | (dst & 255) << 17.

// ---- ONE cooperative kernel: histogram -> scans -> partition ---------------
// 256 blocks x 256 threads (trivially co-resident: 1 block/CU), 3 grid syncs
// replace 3 dispatch boundaries.
__global__ void coop_build(const int* __restrict__ src, const int* __restrict__ dst,
                           int* __restrict__ gcnt, int* __restrict__ btot,
                           int* __restrict__ bstart, int* __restrict__ part,
                           int* __restrict__ ptr, float* __restrict__ add_pool,
                           const float* __restrict__ x, uint4* __restrict__ xb) {
    cg::grid_group grid = cg::this_grid();
    __shared__ int h[CB];
    __shared__ int base[CB];
    __shared__ int s[CBLK];
    int t = threadIdx.x, b = blockIdx.x;

    // Phase A: coarse histogram + xb pack
    for (int i = t; i < CB; i += 256) h[i] = 0;
    __syncthreads();
    int i0 = b * EPB, i1 = min(i0 + EPB, NI4);
    for (int i = i0 + t; i < i1; i += 256) {
        int4 d = ((const int4*)dst)[i];
        atomicAdd(&h[d.x >> 8], 1);
        atomicAdd(&h[d.y >> 8], 1);
        atomicAdd(&h[d.z >> 8], 1);
        atomicAdd(&h[d.w >> 8], 1);
    }
    __syncthreads();
    for (int i = t; i < CB; i += 256) gcnt[b * CB + i] = h[i];
    for (int n = b * 256 + t; n < N_NODES; n += CBLK * 256) {
        const float* xr = x + (size_t)n * IN_DIM;
        uint4 o;
        o.x = pack2(xr[0], xr[1]);
        o.y = pack2(xr[2], xr[3]);
        o.z = pack2(xr[4], 0.0f);
        o.w = 0u;
        xb[n] = o;
    }
    __threadfence();
    grid.sync();

    // Phase B1: per-bucket exclusive scan over the 256 partition blocks
    for (int k = b; k < CB; k += CBLK) {
        int v = gcnt[t * CB + k];
        s[t] = v;
        __syncthreads();
        for (int off = 1; off < CBLK; off <<= 1) {
            int u = (t >= off) ? s[t - off] : 0;
            __syncthreads();
            s[t] += u;
            __syncthreads();
        }
        gcnt[t * CB + k] = s[t] - v;
        if (t == CBLK - 1) btot[k] = s[t];
        __syncthreads();
    }
    __threadfence();
    grid.sync();

    // Phase B2: block 0 scans bucket totals (one wave); block 1 zeros add_pool
    if (b == 0) {
        if (t < 64) {
            int cbase = t * 7;              // 64*7 = 448 >= CB
            int loc[7];
            int sum = 0;
#pragma unroll
            for (int j = 0; j < 7; ++j) {
                int idx = cbase + j;
                int c = (idx < CB) ? btot[idx] : 0;
                loc[j] = sum; sum += c;
            }
            int inc = sum;
#pragma unroll
            for (int off = 1; off < 64; off <<= 1) {
                int u = __shfl_up(inc, off, 64);
                if (t >= off) inc += u;
            }
            int excl = inc - sum;
#pragma unroll
            for (int j = 0; j < 7; ++j) {
                int idx = cbase + j;
                if (idx < CB) bstart[idx] = excl + loc[j];
            }
        }
        if (t == 0) { bstart[CB] = N_EDGES; ptr[N_NODES] = N_EDGES; }
    } else if (b == 1) {
        for (int i = t; i < NUM_GRAPHS * HIDDEN; i += 256) add_pool[i] = 0.0f;
    }
    __threadfence();
    grid.sync();

    // Phase C: partition edges into coarse-bucket order (packed 4B)
    for (int i = t; i < CB; i += 256) {
        base[i] = bstart[i] + gcnt[b * CB + i];
        h[i] = 0;
    }
    __syncthreads();
    for (int i = i0 + t; i < i1; i += 256) {
        int4 s4 = ((const int4*)src)[i];
        int4 d4 = ((const int4*)dst)[i];
        int k, r;
        k = d4.x >> 8; r = atomicAdd(&h[k], 1); part[base[k] + r] = s4.x | ((d4.x & 255) << 17);
        k = d4.y >> 8; r = atomicAdd(&h[k], 1); part[base[k] + r] = s4.y | ((d4.y & 255) << 17);
        k = d4.z >> 8; r = atomicAdd(&h[k], 1); part[base[k] + r] = s4.z | ((d4.z & 255) << 17);
        k = d4.w >> 8; r = atomicAdd(&h[k], 1); part[base[k] + r] = s4.w | ((d4.w & 255) << 17);
    }
}

// ---- Fallback path (if cooperative launch is unavailable): r5 kernels ------
__global__ void coarse_count(const int* __restrict__ dst, int* __restrict__ gcnt,
                             const float* __restrict__ x, uint4* __restrict__ xb) {
    __shared__ int h[CB];
    int t = threadIdx.x, b = blockIdx.x;
    for (int i = t; i < CB; i += 256) h[i] = 0;
    __syncthreads();
    int i0 = b * EPB, i1 = min(i0 + EPB, NI4);
    for (int i = i0 + t; i < i1; i += 256) {
        int4 d = ((const int4*)dst)[i];
        atomicAdd(&h[d.x >> 8], 1);
        atomicAdd(&h[d.y >> 8], 1);
        atomicAdd(&h[d.z >> 8], 1);
        atomicAdd(&h[d.w >> 8], 1);
    }
    __syncthreads();
    for (int i = t; i < CB; i += 256) gcnt[b * CB + i] = h[i];
    for (int n = b * 256 + t; n < N_NODES; n += CBLK * 256) {
        const float* xr = x + (size_t)n * IN_DIM;
        uint4 o;
        o.x = pack2(xr[0], xr[1]);
        o.y = pack2(xr[2], xr[3]);
        o.z = pack2(xr[4], 0.0f);
        o.w = 0u;
        xb[n] = o;
    }
}

__global__ void block_scan(int* __restrict__ gcnt, int* __restrict__ btot) {
    __shared__ int s[CBLK];
    int k = blockIdx.x, t = threadIdx.x;
    int v = gcnt[t * CB + k];
    s[t] = v;
    __syncthreads();
    for (int off = 1; off < CBLK; off <<= 1) {
        int u = (t >= off) ? s[t - off] : 0;
        __syncthreads();
        s[t] += u;
        __syncthreads();
    }
    gcnt[t * CB + k] = s[t] - v;
    if (t == CBLK - 1) btot[k] = s[t];
}

__global__ void bucket_scan(const int* __restrict__ btot, int* __restrict__ bstart,
                            float* __restrict__ add_pool, int* __restrict__ ptr) {
    __shared__ int s[512];
    int t = threadIdx.x;
    int v = (t < CB) ? btot[t] : 0;
    s[t] = v;
    __syncthreads();
    for (int off = 1; off < 512; off <<= 1) {
        int u = (t >= off) ? s[t - off] : 0;
        __syncthreads();
        s[t] += u;
        __syncthreads();
    }
    if (t < CB) bstart[t] = s[t] - v;
    if (t == 0) { bstart[CB] = N_EDGES; ptr[N_NODES] = N_EDGES; }
    for (int i = t; i < NUM_GRAPHS * HIDDEN; i += 512) add_pool[i] = 0.0f;
}

__global__ void partition_k(const int* __restrict__ src, const int* __restrict__ dst,
                            const int* __restrict__ gcnt, const int* __restrict__ bstart,
                            int* __restrict__ part) {
    __shared__ int base[CB];
    __shared__ int h[CB];
    int t = threadIdx.x, b = blockIdx.x;
    for (int i = t; i < CB; i += 256) {
        base[i] = bstart[i] + gcnt[b * CB + i];
        h[i] = 0;
    }
    __syncthreads();
    int i0 = b * EPB, i1 = min(i0 + EPB, NI4);
    for (int i = i0 + t; i < i1; i += 256) {
        int4 s4 = ((const int4*)src)[i];
        int4 d4 = ((const int4*)dst)[i];
        int k, r;
        k = d4.x >> 8; r = atomicAdd(&h[k], 1); part[base[k] + r] = s4.x | ((d4.x & 255) << 17);
        k = d4.y >> 8; r = atomicAdd(&h[k], 1); part[base[k] + r] = s4.y | ((d4.y & 255) << 17);
        k = d4.z >> 8; r = atomicAdd(&h[k], 1); part[base[k] + r] = s4.z | ((d4.z & 255) << 17);
        k = d4.w >> 8; r = atomicAdd(&h[k], 1); part[base[k] + r] = s4.w | ((d4.w & 255) << 17);
    }
}

// ---- Fine sort + Layer 1 (fused): sort, ptr build, gather, MLP -------------
__global__ void fine_gather1(const int* __restrict__ part, const int* __restrict__ bstart,
                             int* __restrict__ ptr, int* __restrict__ esrc,
                             const uint4* __restrict__ xb,
                             const float* __restrict__ x,
                             const float* __restrict__ w_rel1,
                             const float* __restrict__ b_rel1,
                             const float* __restrict__ w_root1,
                             unsigned short* __restrict__ h1,
                             unsigned char* __restrict__ h1f8) {
    __shared__ int fh[256];   // counts, then exclusive offsets (kept for gather)
    __shared__ int fo[256];   // scan workspace
    __shared__ int fr[256];   // scatter cursors
    int k = blockIdx.x, t = threadIdx.x;
    int e0 = bstart[k], e1 = bstart[k + 1];
    fh[t] = 0; fr[t] = 0;
    __syncthreads();
    for (int e = e0 + t; e < e1; e += 256)
        atomicAdd(&fh[(part[e] >> 17) & 255], 1);
    __syncthreads();
    int v = fh[t];
    fo[t] = v;
    __syncthreads();
    for (int off = 1; off < 256; off <<= 1) {
        int u = (t >= off) ? fo[t - off] : 0;
        __syncthreads();
        fo[t] += u;
        __syncthreads();
    }
    int excl = fo[t] - v;
    int n_t = (k << 8) + t;
    if (n_t < N_NODES) ptr[n_t] = e0 + excl;
    fh[t] = excl;
    __syncthreads();
    for (int e = e0 + t; e < e1; e += 256) {
        int p = part[e];
        int d = (p >> 17) & 255;
        int r = atomicAdd(&fr[d], 1);
        esrc[e0 + fh[d] + r] = p & 0x1FFFF;
    }
    __syncthreads();   // this block's esrc region + fh offsets are complete

    // ---- layer-1 gather + transform (16-lane groups, 16 nodes per round) ---
    int ql = t & 15;
    int g  = t >> 4;   // 16 groups per block
    float wr[IN_DIM][4], wo[IN_DIM][4], bias[4];
#pragma unroll
    for (int j = 0; j < 4; ++j) {
        int ch = ql * 4 + j;
        bias[j] = b_rel1[ch];
#pragma unroll
        for (int kk = 0; kk < IN_DIM; ++kk) {
            wr[kk][j] = w_rel1[kk * HIDDEN + ch];
            wo[kk][j] = w_root1[kk * HIDDEN + ch];
        }
    }

    for (int nl = g; nl < 256; nl += 16) {
        int n = (k << 8) + nl;
        if (n >= N_NODES) break;
        int start = e0 + fh[nl];
        int end   = (nl < 255) ? (e0 + fh[nl + 1]) : e1;
        float a[IN_DIM] = {0.f, 0.f, 0.f, 0.f, 0.f};
        for (int e = start + ql; e < end; e += 16) {
            uint4 p = xb[esrc[e]];
            a[0] += blo(p.x); a[1] += bhi(p.x);
            a[2] += blo(p.y); a[3] += bhi(p.y);
            a[4] += blo(p.z);
        }
#pragma unroll
        for (int kk = 0; kk < IN_DIM; ++kk) {
            a[kk] += __shfl_xor(a[kk], 1, 64);
            a[kk] += __shfl_xor(a[kk], 2, 64);
            a[kk] += __shfl_xor(a[kk], 4, 64);
            a[kk] += __shfl_xor(a[kk], 8, 64);
        }
        float xr[IN_DIM];
#pragma unroll
        for (int kk = 0; kk < IN_DIM; ++kk) xr[kk] = x[(size_t)n * IN_DIM + kk];

        unsigned short hv[4];
        unsigned char  hf[4];
#pragma unroll
        for (int j = 0; j < 4; ++j) {
            float acc = bias[j];
#pragma unroll
            for (int kk = 0; kk < IN_DIM; ++kk)
                acc += a[kk] * wr[kk][j] + xr[kk] * wo[kk][j];
            float h = fmaxf(acc, 0.0f);
            hv[j] = f2bs(h);
            hf[j] = f2f8(h);
        }
        ushort4 v4; v4.x = hv[0]; v4.y = hv[1]; v4.z = hv[2]; v4.w = hv[3];
        *(ushort4*)(h1 + (size_t)n * HIDDEN + ql * 4) = v4;
        uchar4 c4; c4.x = hf[0]; c4.y = hf[1]; c4.z = hf[2]; c4.w = hf[3];
        *(uchar4*)(h1f8 + (size_t)n * HIDDEN + ql * 4) = c4;
    }
}

// ==================== GNN compute ===========================================

// ---- Layer 2: 16-lane-group fp8-row gather, 4-deep unroll, HW fp8 decode ---
__global__ void gather2_fp8(const unsigned* __restrict__ rows,   // row = 16 dwords
                            const int* __restrict__ ptr,
                            const int* __restrict__ esrc,
                            uint2* __restrict__ agg2) {          // row = 16 uint2
    int t    = threadIdx.x;
    int ql   = t & 15;
    int grp  = (blockIdx.x * blockDim.x + t) >> 4;
    int ngrp = (gridDim.x * blockDim.x) >> 4;

    for (int n = grp; n < N_NODES; n += ngrp) {
        int start = ptr[n], end = ptr[n + 1];
        float4 a0 = {0.f,0.f,0.f,0.f}, a1 = a0, a2 = a0, a3 = a0;
        int e = start;
        for (; e + 3 < end; e += 4) {
            int s0 = esrc[e], s1 = esrc[e + 1], s2 = esrc[e + 2], s3 = esrc[e + 3];
            unsigned r0 = rows[(size_t)s0 * 16 + ql];
            unsigned r1 = rows[(size_t)s1 * 16 + ql];
            unsigned r2 = rows[(size_t)s2 * 16 + ql];
            unsigned r3 = rows[(size_t)s3 * 16 + ql];
            acc8(a0, r0); acc8(a1, r1); acc8(a2, r2); acc8(a3, r3);
        }
        for (; e < end; ++e) {
            unsigned r0 = rows[(size_t)esrc[e] * 16 + ql];
            acc8(a0, r0);
        }
        float4 a;
        a.x = (a0.x + a1.x) + (a2.x + a3.x);
        a.y = (a0.y + a1.y) + (a2.y + a3.y);
        a.z = (a0.z + a1.z) + (a2.z + a3.z);
        a.w = (a0.w + a1.w) + (a2.w + a3.w);
        uint2 o;
        o.x = pack2(a.x, a.y);
        o.y = pack2(a.z, a.w);
        agg2[(size_t)n * 16 + ql] = o;   // 128B contiguous per node row
    }
}

// ---- Layer 2 transform via MFMA, FUSED with add-pool -----------------------
__global__ void mlp2_pool(const unsigned short* __restrict__ agg2,
                          const unsigned short* __restrict__ h1,
                          const float* __restrict__ w_rel2,
                          const float* __restrict__ b_rel2,
                          const float* __restrict__ w_root2,
                          const int* __restrict__ batch,
                          float* __restrict__ add_pool) {
    int lane = threadIdx.x & 63;
    int wv   = threadIdx.x >> 6;
    int row  = lane & 15;
    int quad = lane >> 4;
    int n    = wv * 16 + row;           // this lane's output column

    short8 bwr[2], bwo[2];
#pragma unroll
    for (int s = 0; s < 2; ++s)
#pragma unroll
        for (int j = 0; j < 8; ++j) {
            int k = 32 * s + quad * 8 + j;
            bwr[s][j] = (short)f2bs(w_rel2[k * HIDDEN + n]);
            bwo[s][j] = (short)f2bs(w_root2[k * HIDDEN + n]);
        }
    float bias = b_rel2[n];

    for (int t = blockIdx.x; t < M_TILES; t += gridDim.x) {
        int m0 = t * 16;
        size_t rbase = (size_t)(m0 + row) * HIDDEN;
        short8 aa0 = *(const short8*)(agg2 + rbase + quad * 8);
        short8 aa1 = *(const short8*)(agg2 + rbase + 32 + quad * 8);
        short8 ah0 = *(const short8*)(h1   + rbase + quad * 8);
        short8 ah1 = *(const short8*)(h1   + rbase + 32 + quad * 8);

        f32x4 acc = {bias, bias, bias, bias};
        acc = __builtin_amdgcn_mfma_f32_16x16x32_bf16(aa0, bwr[0], acc, 0, 0, 0);
        acc = __builtin_amdgcn_mfma_f32_16x16x32_bf16(aa1, bwr[1], acc, 0, 0, 0);
        acc = __builtin_amdgcn_mfma_f32_16x16x32_bf16(ah0, bwo[0], acc, 0, 0, 0);
        acc = __builtin_amdgcn_mfma_f32_16x16x32_bf16(ah1, bwo[1], acc, 0, 0, 0);

        float hv0 = fmaxf(acc[0], 0.0f), hv1 = fmaxf(acc[1], 0.0f);
        float hv2 = fmaxf(acc[2], 0.0f), hv3 = fmaxf(acc[3], 0.0f);

        int gLo = batch[m0], gHi = batch[m0 + 15];
        if (gLo == gHi) {
            float s = (hv0 + hv1) + (hv2 + hv3);
            s += __shfl_xor(s, 16, 64);
            s += __shfl_xor(s, 32, 64);
            if (quad == 0)
                atomicAdd(&add_pool[gLo * HIDDEN + n], s);
        } else {
            int m = m0 + quad * 4;
            atomicAdd(&add_pool[batch[m]     * HIDDEN + n], hv0);
            atomicAdd(&add_pool[batch[m + 1] * HIDDEN + n], hv1);
            atomicAdd(&add_pool[batch[m + 2] * HIDDEN + n], hv2);
            atomicAdd(&add_pool[batch[m + 3] * HIDDEN + n], hv3);
        }
    }
}

// ---- MLP head: one block (64 threads) per graph ----------------------------
__device__ __forceinline__ int lower_bound_i(const int* a, int n, int v) {
    int lo = 0, hi = n;
    while (lo < hi) { int mid = (lo + hi) >> 1; if (a[mid] < v) lo = mid + 1; else hi = mid; }
    return lo;
}

__global__ void head_mlp(const float* __restrict__ add_pool,
                         const int* __restrict__ batch,
                         const float* __restrict__ w_h1,
                         const float* __restrict__ b_h1,
                         const float* __restrict__ w_h2,
                         const float* __restrict__ b_h2,
                         float* __restrict__ out) {
    int g = blockIdx.x, t = threadIdx.x;

    __shared__ int s_cnt;
    if (t == 0) {
        int start = lower_bound_i(batch, N_NODES, g);
        int end   = lower_bound_i(batch, N_NODES, g + 1);
        s_cnt = end - start;
    }
    __syncthreads();
    float cnt = fmaxf((float)s_cnt, 1.0f);

    __shared__ float sg[2 * HIDDEN];
    float add = add_pool[(size_t)g * HIDDEN + t];
    sg[t]          = add / cnt;   // mean_pool
    sg[HIDDEN + t] = add;         // add_pool
    __syncthreads();

    float hid = b_h1[t];
#pragma unroll 16
    for (int i = 0; i < 2 * HIDDEN; ++i)
        hid += sg[i] * w_h1[i * HIDDEN + t];
    hid = fmaxf(hid, 0.0f);

    float res = hid * w_h2[t];
    for (int off = 32; off > 0; off >>= 1)
        res += __shfl_down(res, off, 64);
    if (t == 0) out[g] = res + b_h2[0];
}

extern "C" void kernel_launch(void* const* d_in, const int* in_sizes, int n_in,
                              void* d_out, int out_size, void* d_ws, size_t ws_size,
                              hipStream_t stream) {
    const float* x       = (const float*)d_in[0];
    const int*   ei      = (const int*)d_in[1];
    const int*   src     = ei;
    const int*   dst     = ei + N_EDGES;
    const int*   batch   = (const int*)d_in[2];
    const float* w_rel1  = (const float*)d_in[3];
    const float* b_rel1  = (const float*)d_in[4];
    const float* w_root1 = (const float*)d_in[5];
    const float* w_rel2  = (const float*)d_in[6];
    const float* b_rel2  = (const float*)d_in[7];
    const float* w_root2 = (const float*)d_in[8];
    const float* w_h1    = (const float*)d_in[9];
    const float* b_h1    = (const float*)d_in[10];
    const float* w_h2    = (const float*)d_in[11];
    const float* b_h2    = (const float*)d_in[12];
    float* out = (float*)d_out;

    int* base = (int*)d_ws;
    int*   gcnt     = base;                                   // CBLK*CB
    int*   btot     = gcnt + ((CBLK * CB + 3) & ~3);          // CB
    int*   bstart   = btot + ((CB + 3) & ~3);                 // CB+1
    float* add_pool = (float*)(bstart + ((CB + 1 + 3) & ~3)); // 128*64 f32
    int*   ptr      = (int*)(add_pool + NUM_GRAPHS * HIDDEN); // N+1
    int*   part     = ptr + ((N_NODES + 1 + 3) & ~3);         // E packed ints
    int*   esrc     = part + N_EDGES;                         // E
    unsigned short* h1   = (unsigned short*)(esrc + N_EDGES); // N*64 bf16
    unsigned short* agg2 = h1 + (size_t)N_NODES * HIDDEN;     // N*64 bf16
    unsigned char*  h1f8 = (unsigned char*)(agg2 + (size_t)N_NODES * HIDDEN); // N*64 fp8
    uint4*          xb   = (uint4*)(h1f8 + (size_t)N_NODES * HIDDEN);         // N*16B

    // ---- CSR build: ONE cooperative dispatch (3 grid syncs), with fallback --
    {
        void* ka[] = { (void*)&src, (void*)&dst, (void*)&gcnt, (void*)&btot,
                       (void*)&bstart, (void*)&part, (void*)&ptr, (void*)&add_pool,
                       (void*)&x, (void*)&xb };
        hipError_t err = hipLaunchCooperativeKernel((const void*)coop_build,
                                                    dim3(CBLK), dim3(256), ka, 0, stream);
        if (err != hipSuccess) {
            // fallback: 4-dispatch build (identical semantics)
            coarse_count<<<CBLK, 256, 0, stream>>>(dst, gcnt, x, xb);
            block_scan<<<CB, CBLK, 0, stream>>>(gcnt, btot);
            bucket_scan<<<1, 512, 0, stream>>>(btot, bstart, add_pool, ptr);
            partition_k<<<CBLK, 256, 0, stream>>>(src, dst, gcnt, bstart, part);
        }
    }

    // ---- Fine sort + Layer 1 (fused: sort, ptr build, gather, MLP) ----
    fine_gather1<<<CB, 256, 0, stream>>>(part, bstart, ptr, esrc, xb, x,
                                         w_rel1, b_rel1, w_root1, h1, h1f8);
    // ---- Layer 2 gather (16-lane groups, 4-deep unroll, HW fp8 decode) ----
    gather2_fp8<<<2048, 256, 0, stream>>>((const unsigned*)h1f8, ptr, esrc, (uint2*)agg2);
    // ---- Layer 2 transform (MFMA) + add-pool ----
    mlp2_pool<<<2048, 256, 0, stream>>>(agg2, h1, w_rel2, b_rel2, w_root2, batch, add_pool);
    // ---- Head ----
    head_mlp<<<NUM_GRAPHS, 64, 0, stream>>>(add_pool, batch, w_h1, b_h1, w_h2, b_h2, out);
}

// Round 7
// 227.855 us; speedup vs baseline: 1.6272x; 1.6272x over previous
//
#include <hip/hip_runtime.h>
#include <hip/hip_bf16.h>

#define N_NODES    100000
#define N_EDGES    1200000
#define NUM_GRAPHS 128
#define IN_DIM     5
#define HIDDEN     64
#define M_TILES    (N_NODES / 16)   // 6250 (exact)
#define NI4        (N_EDGES / 4)    // 300000 int4 groups

#define CB    782                   // coarse buckets of 128 nodes: ceil(N/128)
#define CBLK  256                   // partition blocks
#define EPB   ((NI4 + CBLK - 1) / CBLK)   // 1172 int4-groups per block

typedef __attribute__((ext_vector_type(8))) short short8;   // 8 bf16 (4 VGPRs)
typedef __attribute__((ext_vector_type(4))) float f32x4;
typedef __attribute__((ext_vector_type(2))) float f32x2;

#if defined(__has_builtin)
#if __has_builtin(__builtin_amdgcn_cvt_pk_f32_fp8)
#define HAS_HWF8 1
#endif
#endif

// fp32 -> bf16 bits (RNE)
__device__ __forceinline__ unsigned short f2bs(float f) {
    union { float f; unsigned u; } v; v.f = f;
    return (unsigned short)((v.u + 0x7FFFu + ((v.u >> 16) & 1u)) >> 16);
}
// bf16 bits -> fp32
__device__ __forceinline__ float bs2f(unsigned short s) {
    union { unsigned u; float f; } v; v.u = ((unsigned)s) << 16;
    return v.f;
}
__device__ __forceinline__ float blo(unsigned p) { return bs2f((unsigned short)(p & 0xffff)); }
__device__ __forceinline__ float bhi(unsigned p) { return bs2f((unsigned short)(p >> 16)); }
__device__ __forceinline__ unsigned pack2(float a, float b) {
    return ((unsigned)f2bs(b) << 16) | (unsigned)f2bs(a);
}

// fp32 (>=0) -> fp8 e4m3 bits (OCP), RNE, denorm-exact (magic-multiply trick)
__device__ __forceinline__ unsigned char f2f8(float f) {
    union { float f; unsigned u; } v; v.f = f * 0x1p-120f;
    unsigned u = v.u + 0x7FFFFu + ((v.u >> 20) & 1u);
    return (unsigned char)(u >> 20);
}
// fp8 e4m3 bits -> fp32 (exact inverse)
__device__ __forceinline__ float f82f(unsigned b) {
    union { unsigned u; float f; } v; v.u = (b & 0x7Fu) << 20;
    return v.f * 0x1p120f;
}

// accumulate 4 fp8 bytes of r into a (HW decode when available; bit-identical)
__device__ __forceinline__ void acc8(float4& a, unsigned r) {
#ifdef HAS_HWF8
    f32x2 lo = __builtin_amdgcn_cvt_pk_f32_fp8((int)r, false);
    f32x2 hi = __builtin_amdgcn_cvt_pk_f32_fp8((int)r, true);
    a.x += lo[0]; a.y += lo[1]; a.z += hi[0]; a.w += hi[1];
#else
    a.x += f82f(r); a.y += f82f(r >> 8); a.z += f82f(r >> 16); a.w += f82f(r >> 24);
#endif
}

// ==================== CSR build: two-level counting sort ====================
// part entries are PACKED 4B: src (bits 0..16) | (dst & 127) << 17.
// No grid sync anywhere (r6 lesson: grid.sync ~45us on MI355X). Dispatch
// boundaries minimized instead via the redundant-scan trick in partition_k.

// ---- Pass A: coarse histogram (dst>>7, LDS) + xb pack + misc init ----------
__global__ void coarse_count(const int* __restrict__ dst, int* __restrict__ gcnt,
                             const float* __restrict__ x, uint4* __restrict__ xb,
                             float* __restrict__ add_pool, int* __restrict__ ptr) {
    __shared__ int h[CB];
    int t = threadIdx.x, b = blockIdx.x;
    for (int i = t; i < CB; i += 256) h[i] = 0;
    __syncthreads();
    int i0 = b * EPB, i1 = min(i0 + EPB, NI4);
    for (int i = i0 + t; i < i1; i += 256) {
        int4 d = ((const int4*)dst)[i];
        atomicAdd(&h[d.x >> 7], 1);
        atomicAdd(&h[d.y >> 7], 1);
        atomicAdd(&h[d.z >> 7], 1);
        atomicAdd(&h[d.w >> 7], 1);
    }
    __syncthreads();
    for (int i = t; i < CB; i += 256) gcnt[b * CB + i] = h[i];

    // fold: pack x rows into 16B (5 bf16 + pad) for the layer-1 edge gather
    for (int n = b * 256 + t; n < N_NODES; n += CBLK * 256) {
        const float* xr = x + (size_t)n * IN_DIM;
        uint4 o;
        o.x = pack2(xr[0], xr[1]);
        o.y = pack2(xr[2], xr[3]);
        o.z = pack2(xr[4], 0.0f);
        o.w = 0u;
        xb[n] = o;
    }
    // fold: zero add_pool, terminate ptr
    if (b == 0) {
        for (int i = t; i < NUM_GRAPHS * HIDDEN; i += 256) add_pool[i] = 0.0f;
        if (t == 0) ptr[N_NODES] = N_EDGES;
    }
}

// ---- Pass B: partition with REDUNDANT SELF-SCAN (replaces 2 scan kernels) --
// Every block recomputes the (bucket,block) exclusive offsets itself from
// gcnt (800KB, L2-hot; coalesced row reads). ~6us chip-wide redundant work
// buys the removal of 2 dispatch boundaries. Block 0 publishes bstart.
__global__ void partition_k(const int* __restrict__ src, const int* __restrict__ dst,
                            const int* __restrict__ gcnt, int* __restrict__ bstart,
                            int* __restrict__ part) {
    __shared__ int sp[CB];    // colpref (then base cursors)
    __shared__ int st[CB];    // coltot  (then bstart)
    __shared__ int h[CB];     // scatter cursors
    int t = threadIdx.x, b = blockIdx.x;

    // column sums over the 256 block rows (coalesced: adjacent t -> adjacent k)
    for (int k = t; k < CB; k += 256) {
        int pref = 0, tot = 0;
        for (int bp = 0; bp < CBLK; ++bp) {
            int v = gcnt[bp * CB + k];
            tot += v;
            if (bp < b) pref += v;
        }
        sp[k] = pref;
        st[k] = tot;
        h[k] = 0;
    }
    __syncthreads();

    // exclusive scan of st[0..CB) by wave 0 (13 entries/lane + shuffle scan)
    if (t < 64) {
        int loc[13];                      // 64*13 = 832 >= CB
        int base_i = t * 13;
        int sum = 0;
#pragma unroll
        for (int j = 0; j < 13; ++j) {
            int idx = base_i + j;
            int c = (idx < CB) ? st[idx] : 0;
            loc[j] = sum; sum += c;
        }
        int inc = sum;
#pragma unroll
        for (int off = 1; off < 64; off <<= 1) {
            int u = __shfl_up(inc, off, 64);
            if (t >= off) inc += u;
        }
        int excl = inc - sum;
#pragma unroll
        for (int j = 0; j < 13; ++j) {
            int idx = base_i + j;
            if (idx < CB) st[idx] = excl + loc[j];
        }
    }
    __syncthreads();

    // base cursors; block 0 publishes bstart for the fine pass
    for (int k = t; k < CB; k += 256) {
        int bs = st[k];
        sp[k] = bs + sp[k];
        if (b == 0) bstart[k] = bs;
    }
    if (b == 0 && t == 0) bstart[CB] = N_EDGES;
    __syncthreads();

    // scatter into private contiguous regions (packed 4B)
    int i0 = b * EPB, i1 = min(i0 + EPB, NI4);
    for (int i = i0 + t; i < i1; i += 256) {
        int4 s4 = ((const int4*)src)[i];
        int4 d4 = ((const int4*)dst)[i];
        int k, r;
        k = d4.x >> 7; r = atomicAdd(&h[k], 1); part[sp[k] + r] = s4.x | ((d4.x & 127) << 17);
        k = d4.y >> 7; r = atomicAdd(&h[k], 1); part[sp[k] + r] = s4.y | ((d4.y & 127) << 17);
        k = d4.z >> 7; r = atomicAdd(&h[k], 1); part[sp[k] + r] = s4.z | ((d4.z & 127) << 17);
        k = d4.w >> 7; r = atomicAdd(&h[k], 1); part[sp[k] + r] = s4.w | ((d4.w & 127) << 17);
    }
}

// ---- Pass C FUSED with Layer 1: fine sort + ptr + gather + MLP -------------
// One block per 128-node bucket (782 blocks -> ~3/CU occupancy).
__global__ void fine_gather1(const int* __restrict__ part, const int* __restrict__ bstart,
                             int* __restrict__ ptr, int* __restrict__ esrc,
                             const uint4* __restrict__ xb,
                             const float* __restrict__ x,
                             const float* __restrict__ w_rel1,
                             const float* __restrict__ b_rel1,
                             const float* __restrict__ w_root1,
                             unsigned short* __restrict__ h1,
                             unsigned char* __restrict__ h1f8) {
    __shared__ int fh[128];   // counts, then exclusive offsets (kept for gather)
    __shared__ int fo[128];   // scan workspace
    __shared__ int fr[128];   // scatter cursors
    int k = blockIdx.x, t = threadIdx.x;
    int e0 = bstart[k], e1 = bstart[k + 1];
    if (t < 128) { fh[t] = 0; fr[t] = 0; }
    __syncthreads();
    for (int e = e0 + t; e < e1; e += 256)
        atomicAdd(&fh[(part[e] >> 17) & 127], 1);
    __syncthreads();
    int v = (t < 128) ? fh[t] : 0;
    if (t < 128) fo[t] = v;
    __syncthreads();
    for (int off = 1; off < 128; off <<= 1) {
        int u = (t >= off && t < 128) ? fo[t - off] : 0;
        __syncthreads();
        if (t < 128) fo[t] += u;
        __syncthreads();
    }
    if (t < 128) {
        int excl = fo[t] - v;
        int n_t = (k << 7) + t;
        if (n_t < N_NODES) ptr[n_t] = e0 + excl;
        fh[t] = excl;
    }
    __syncthreads();
    for (int e = e0 + t; e < e1; e += 256) {
        int p = part[e];
        int d = (p >> 17) & 127;
        int r = atomicAdd(&fr[d], 1);
        esrc[e0 + fh[d] + r] = p & 0x1FFFF;
    }
    __syncthreads();   // this block's esrc region + fh offsets are complete

    // ---- layer-1 gather + transform (16-lane groups, 8 node rounds) --------
    int ql = t & 15;
    int g  = t >> 4;   // 16 groups per block
    float wr[IN_DIM][4], wo[IN_DIM][4], bias[4];
#pragma unroll
    for (int j = 0; j < 4; ++j) {
        int ch = ql * 4 + j;
        bias[j] = b_rel1[ch];
#pragma unroll
        for (int kk = 0; kk < IN_DIM; ++kk) {
            wr[kk][j] = w_rel1[kk * HIDDEN + ch];
            wo[kk][j] = w_root1[kk * HIDDEN + ch];
        }
    }

    for (int nl = g; nl < 128; nl += 16) {
        int n = (k << 7) + nl;
        if (n >= N_NODES) break;
        int start = e0 + fh[nl];
        int end   = (nl < 127) ? (e0 + fh[nl + 1]) : e1;
        float a[IN_DIM] = {0.f, 0.f, 0.f, 0.f, 0.f};
        for (int e = start + ql; e < end; e += 16) {
            uint4 p = xb[esrc[e]];
            a[0] += blo(p.x); a[1] += bhi(p.x);
            a[2] += blo(p.y); a[3] += bhi(p.y);
            a[4] += blo(p.z);
        }
#pragma unroll
        for (int kk = 0; kk < IN_DIM; ++kk) {
            a[kk] += __shfl_xor(a[kk], 1, 64);
            a[kk] += __shfl_xor(a[kk], 2, 64);
            a[kk] += __shfl_xor(a[kk], 4, 64);
            a[kk] += __shfl_xor(a[kk], 8, 64);
        }
        float xr[IN_DIM];
#pragma unroll
        for (int kk = 0; kk < IN_DIM; ++kk) xr[kk] = x[(size_t)n * IN_DIM + kk];

        unsigned short hv[4];
        unsigned char  hf[4];
#pragma unroll
        for (int j = 0; j < 4; ++j) {
            float acc = bias[j];
#pragma unroll
            for (int kk = 0; kk < IN_DIM; ++kk)
                acc += a[kk] * wr[kk][j] + xr[kk] * wo[kk][j];
            float h = fmaxf(acc, 0.0f);
            hv[j] = f2bs(h);
            hf[j] = f2f8(h);
        }
        ushort4 v4; v4.x = hv[0]; v4.y = hv[1]; v4.z = hv[2]; v4.w = hv[3];
        *(ushort4*)(h1 + (size_t)n * HIDDEN + ql * 4) = v4;
        uchar4 c4; c4.x = hf[0]; c4.y = hf[1]; c4.z = hf[2]; c4.w = hf[3];
        *(uchar4*)(h1f8 + (size_t)n * HIDDEN + ql * 4) = c4;
    }
}

// ==================== GNN compute ===========================================

// ---- Layer 2: 16-lane-group fp8-row gather, 4-deep unroll, HW fp8 decode ---
__global__ void gather2_fp8(const unsigned* __restrict__ rows,   // row = 16 dwords
                            const int* __restrict__ ptr,
                            const int* __restrict__ esrc,
                            uint2* __restrict__ agg2) {          // row = 16 uint2
    int t    = threadIdx.x;
    int ql   = t & 15;
    int grp  = (blockIdx.x * blockDim.x + t) >> 4;
    int ngrp = (gridDim.x * blockDim.x) >> 4;

    for (int n = grp; n < N_NODES; n += ngrp) {
        int start = ptr[n], end = ptr[n + 1];
        float4 a0 = {0.f,0.f,0.f,0.f}, a1 = a0, a2 = a0, a3 = a0;
        int e = start;
        for (; e + 3 < end; e += 4) {
            int s0 = esrc[e], s1 = esrc[e + 1], s2 = esrc[e + 2], s3 = esrc[e + 3];
            unsigned r0 = rows[(size_t)s0 * 16 + ql];
            unsigned r1 = rows[(size_t)s1 * 16 + ql];
            unsigned r2 = rows[(size_t)s2 * 16 + ql];
            unsigned r3 = rows[(size_t)s3 * 16 + ql];
            acc8(a0, r0); acc8(a1, r1); acc8(a2, r2); acc8(a3, r3);
        }
        for (; e < end; ++e) {
            unsigned r0 = rows[(size_t)esrc[e] * 16 + ql];
            acc8(a0, r0);
        }
        float4 a;
        a.x = (a0.x + a1.x) + (a2.x + a3.x);
        a.y = (a0.y + a1.y) + (a2.y + a3.y);
        a.z = (a0.z + a1.z) + (a2.z + a3.z);
        a.w = (a0.w + a1.w) + (a2.w + a3.w);
        uint2 o;
        o.x = pack2(a.x, a.y);
        o.y = pack2(a.z, a.w);
        agg2[(size_t)n * 16 + ql] = o;   // 128B contiguous per node row
    }
}

// ---- Layer 2 transform via MFMA, FUSED with add-pool -----------------------
__global__ void mlp2_pool(const unsigned short* __restrict__ agg2,
                          const unsigned short* __restrict__ h1,
                          const float* __restrict__ w_rel2,
                          const float* __restrict__ b_rel2,
                          const float* __restrict__ w_root2,
                          const int* __restrict__ batch,
                          float* __restrict__ add_pool) {
    int lane = threadIdx.x & 63;
    int wv   = threadIdx.x >> 6;
    int row  = lane & 15;
    int quad = lane >> 4;
    int n    = wv * 16 + row;           // this lane's output column

    short8 bwr[2], bwo[2];
#pragma unroll
    for (int s = 0; s < 2; ++s)
#pragma unroll
        for (int j = 0; j < 8; ++j) {
            int k = 32 * s + quad * 8 + j;
            bwr[s][j] = (short)f2bs(w_rel2[k * HIDDEN + n]);
            bwo[s][j] = (short)f2bs(w_root2[k * HIDDEN + n]);
        }
    float bias = b_rel2[n];

    for (int t = blockIdx.x; t < M_TILES; t += gridDim.x) {
        int m0 = t * 16;
        size_t rbase = (size_t)(m0 + row) * HIDDEN;
        short8 aa0 = *(const short8*)(agg2 + rbase + quad * 8);
        short8 aa1 = *(const short8*)(agg2 + rbase + 32 + quad * 8);
        short8 ah0 = *(const short8*)(h1   + rbase + quad * 8);
        short8 ah1 = *(const short8*)(h1   + rbase + 32 + quad * 8);

        f32x4 acc = {bias, bias, bias, bias};
        acc = __builtin_amdgcn_mfma_f32_16x16x32_bf16(aa0, bwr[0], acc, 0, 0, 0);
        acc = __builtin_amdgcn_mfma_f32_16x16x32_bf16(aa1, bwr[1], acc, 0, 0, 0);
        acc = __builtin_amdgcn_mfma_f32_16x16x32_bf16(ah0, bwo[0], acc, 0, 0, 0);
        acc = __builtin_amdgcn_mfma_f32_16x16x32_bf16(ah1, bwo[1], acc, 0, 0, 0);

        float hv0 = fmaxf(acc[0], 0.0f), hv1 = fmaxf(acc[1], 0.0f);
        float hv2 = fmaxf(acc[2], 0.0f), hv3 = fmaxf(acc[3], 0.0f);

        int gLo = batch[m0], gHi = batch[m0 + 15];
        if (gLo == gHi) {
            float s = (hv0 + hv1) + (hv2 + hv3);
            s += __shfl_xor(s, 16, 64);
            s += __shfl_xor(s, 32, 64);
            if (quad == 0)
                atomicAdd(&add_pool[gLo * HIDDEN + n], s);
        } else {
            int m = m0 + quad * 4;
            atomicAdd(&add_pool[batch[m]     * HIDDEN + n], hv0);
            atomicAdd(&add_pool[batch[m + 1] * HIDDEN + n], hv1);
            atomicAdd(&add_pool[batch[m + 2] * HIDDEN + n], hv2);
            atomicAdd(&add_pool[batch[m + 3] * HIDDEN + n], hv3);
        }
    }
}

// ---- MLP head: one block (64 threads) per graph ----------------------------
__device__ __forceinline__ int lower_bound_i(const int* a, int n, int v) {
    int lo = 0, hi = n;
    while (lo < hi) { int mid = (lo + hi) >> 1; if (a[mid] < v) lo = mid + 1; else hi = mid; }
    return lo;
}

__global__ void head_mlp(const float* __restrict__ add_pool,
                         const int* __restrict__ batch,
                         const float* __restrict__ w_h1,
                         const float* __restrict__ b_h1,
                         const float* __restrict__ w_h2,
                         const float* __restrict__ b_h2,
                         float* __restrict__ out) {
    int g = blockIdx.x, t = threadIdx.x;

    __shared__ int s_cnt;
    if (t == 0) {
        int start = lower_bound_i(batch, N_NODES, g);
        int end   = lower_bound_i(batch, N_NODES, g + 1);
        s_cnt = end - start;
    }
    __syncthreads();
    float cnt = fmaxf((float)s_cnt, 1.0f);

    __shared__ float sg[2 * HIDDEN];
    float add = add_pool[(size_t)g * HIDDEN + t];
    sg[t]          = add / cnt;   // mean_pool
    sg[HIDDEN + t] = add;         // add_pool
    __syncthreads();

    float hid = b_h1[t];
#pragma unroll 16
    for (int i = 0; i < 2 * HIDDEN; ++i)
        hid += sg[i] * w_h1[i * HIDDEN + t];
    hid = fmaxf(hid, 0.0f);

    float res = hid * w_h2[t];
    for (int off = 32; off > 0; off >>= 1)
        res += __shfl_down(res, off, 64);
    if (t == 0) out[g] = res + b_h2[0];
}

extern "C" void kernel_launch(void* const* d_in, const int* in_sizes, int n_in,
                              void* d_out, int out_size, void* d_ws, size_t ws_size,
                              hipStream_t stream) {
    const float* x       = (const float*)d_in[0];
    const int*   ei      = (const int*)d_in[1];
    const int*   src     = ei;
    const int*   dst     = ei + N_EDGES;
    const int*   batch   = (const int*)d_in[2];
    const float* w_rel1  = (const float*)d_in[3];
    const float* b_rel1  = (const float*)d_in[4];
    const float* w_root1 = (const float*)d_in[5];
    const float* w_rel2  = (const float*)d_in[6];
    const float* b_rel2  = (const float*)d_in[7];
    const float* w_root2 = (const float*)d_in[8];
    const float* w_h1    = (const float*)d_in[9];
    const float* b_h1    = (const float*)d_in[10];
    const float* w_h2    = (const float*)d_in[11];
    const float* b_h2    = (const float*)d_in[12];
    float* out = (float*)d_out;

    int* base = (int*)d_ws;
    int*   gcnt     = base;                                   // CBLK*CB
    int*   bstart   = gcnt + ((CBLK * CB + 3) & ~3);          // CB+1
    float* add_pool = (float*)(bstart + ((CB + 1 + 3) & ~3)); // 128*64 f32
    int*   ptr      = (int*)(add_pool + NUM_GRAPHS * HIDDEN); // N+1
    int*   part     = ptr + ((N_NODES + 1 + 3) & ~3);         // E packed ints
    int*   esrc     = part + N_EDGES;                         // E
    unsigned short* h1   = (unsigned short*)(esrc + N_EDGES); // N*64 bf16
    unsigned short* agg2 = h1 + (size_t)N_NODES * HIDDEN;     // N*64 bf16
    unsigned char*  h1f8 = (unsigned char*)(agg2 + (size_t)N_NODES * HIDDEN); // N*64 fp8
    uint4*          xb   = (uint4*)(h1f8 + (size_t)N_NODES * HIDDEN);         // N*16B

    // ---- CSR build: 2 dispatches (scan kernels folded into partition) ----
    coarse_count<<<CBLK, 256, 0, stream>>>(dst, gcnt, x, xb, add_pool, ptr);
    partition_k<<<CBLK, 256, 0, stream>>>(src, dst, gcnt, bstart, part);

    // ---- Fine sort + Layer 1 (fused: sort, ptr build, gather, MLP) ----
    fine_gather1<<<CB, 256, 0, stream>>>(part, bstart, ptr, esrc, xb, x,
                                         w_rel1, b_rel1, w_root1, h1, h1f8);
    // ---- Layer 2 gather (16-lane groups, 4-deep unroll, HW fp8 decode) ----
    gather2_fp8<<<2048, 256, 0, stream>>>((const unsigned*)h1f8, ptr, esrc, (uint2*)agg2);
    // ---- Layer 2 transform (MFMA) + add-pool ----
    mlp2_pool<<<2048, 256, 0, stream>>>(agg2, h1, w_rel2, b_rel2, w_root2, batch, add_pool);
    // ---- Head ----
    head_mlp<<<NUM_GRAPHS, 64, 0, stream>>>(add_pool, batch, w_h1, b_h1, w_h2, b_h2, out);
}

// Round 8
// 195.417 us; speedup vs baseline: 1.8973x; 1.1660x over previous
//
#include <hip/hip_runtime.h>
#include <hip/hip_bf16.h>

#define N_NODES    100000
#define N_EDGES    1200000
#define NUM_GRAPHS 128
#define IN_DIM     5
#define HIDDEN     64
#define M_TILES    (N_NODES / 16)   // 6250 (exact)
#define NI4        (N_EDGES / 4)    // 300000 int4 groups

#define CB    782                   // coarse buckets of 128 nodes: ceil(N/128)
#define CBLK  256                   // partition blocks
#define EPB   ((NI4 + CBLK - 1) / CBLK)   // 1172 int4-groups per block
#define STCAP 3072                  // LDS edge-payload capacity (avg 1534/bucket)

typedef __attribute__((ext_vector_type(8))) short short8;   // 8 bf16 (4 VGPRs)
typedef __attribute__((ext_vector_type(4))) float f32x4;
typedef __attribute__((ext_vector_type(2))) float f32x2;

#if defined(__has_builtin)
#if __has_builtin(__builtin_amdgcn_cvt_pk_f32_fp8)
#define HAS_HWF8 1
#endif
#endif

// fp32 -> bf16 bits (RNE)
__device__ __forceinline__ unsigned short f2bs(float f) {
    union { float f; unsigned u; } v; v.f = f;
    return (unsigned short)((v.u + 0x7FFFu + ((v.u >> 16) & 1u)) >> 16);
}
// bf16 bits -> fp32
__device__ __forceinline__ float bs2f(unsigned short s) {
    union { unsigned u; float f; } v; v.u = ((unsigned)s) << 16;
    return v.f;
}
__device__ __forceinline__ float blo(unsigned p) { return bs2f((unsigned short)(p & 0xffff)); }
__device__ __forceinline__ float bhi(unsigned p) { return bs2f((unsigned short)(p >> 16)); }
__device__ __forceinline__ unsigned pack2(float a, float b) {
    return ((unsigned)f2bs(b) << 16) | (unsigned)f2bs(a);
}

// fp32 (>=0) -> fp8 e4m3 bits (OCP), RNE, denorm-exact (magic-multiply trick)
__device__ __forceinline__ unsigned char f2f8(float f) {
    union { float f; unsigned u; } v; v.f = f * 0x1p-120f;
    unsigned u = v.u + 0x7FFFFu + ((v.u >> 20) & 1u);
    return (unsigned char)(u >> 20);
}
// fp8 e4m3 bits -> fp32 (exact inverse)
__device__ __forceinline__ float f82f(unsigned b) {
    union { unsigned u; float f; } v; v.u = (b & 0x7Fu) << 20;
    return v.f * 0x1p120f;
}

// accumulate 4 fp8 bytes of r into a (HW decode when available; bit-identical)
__device__ __forceinline__ void acc8(float4& a, unsigned r) {
#ifdef HAS_HWF8
    f32x2 lo = __builtin_amdgcn_cvt_pk_f32_fp8((int)r, false);
    f32x2 hi = __builtin_amdgcn_cvt_pk_f32_fp8((int)r, true);
    a.x += lo[0]; a.y += lo[1]; a.z += hi[0]; a.w += hi[1];
#else
    a.x += f82f(r); a.y += f82f(r >> 8); a.z += f82f(r >> 16); a.w += f82f(r >> 24);
#endif
}

// ==================== CSR build: two-level counting sort ====================
// part entries are PACKED 4B: src (bits 0..16) | (dst & 127) << 17.
// Lessons baked in: no grid.sync (r6: ~45us each); no redundant self-scan
// (r7: latency-bound, 65us); small scan dispatches are ~5us each and fine.

// ---- Pass A: coarse histogram (dst>>7, LDS) + xb pack + misc init ----------
__global__ void coarse_count(const int* __restrict__ dst, int* __restrict__ gcnt,
                             const float* __restrict__ x, uint4* __restrict__ xb,
                             float* __restrict__ add_pool, int* __restrict__ ptr) {
    __shared__ int h[CB];
    int t = threadIdx.x, b = blockIdx.x;
    for (int i = t; i < CB; i += 256) h[i] = 0;
    __syncthreads();
    int i0 = b * EPB, i1 = min(i0 + EPB, NI4);
    for (int i = i0 + t; i < i1; i += 256) {
        int4 d = ((const int4*)dst)[i];
        atomicAdd(&h[d.x >> 7], 1);
        atomicAdd(&h[d.y >> 7], 1);
        atomicAdd(&h[d.z >> 7], 1);
        atomicAdd(&h[d.w >> 7], 1);
    }
    __syncthreads();
    for (int i = t; i < CB; i += 256) gcnt[b * CB + i] = h[i];

    // fold: pack x rows into 16B (5 bf16 + pad) for the layer-1 edge gather
    for (int n = b * 256 + t; n < N_NODES; n += CBLK * 256) {
        const float* xr = x + (size_t)n * IN_DIM;
        uint4 o;
        o.x = pack2(xr[0], xr[1]);
        o.y = pack2(xr[2], xr[3]);
        o.z = pack2(xr[4], 0.0f);
        o.w = 0u;
        xb[n] = o;
    }
    // fold: zero add_pool, terminate ptr
    if (b == 0) {
        for (int i = t; i < NUM_GRAPHS * HIDDEN; i += 256) add_pool[i] = 0.0f;
        if (t == 0) ptr[N_NODES] = N_EDGES;
    }
}

// ---- Pass B1: per-bucket exclusive scan over the 256 partition blocks ------
__global__ void block_scan(int* __restrict__ gcnt, int* __restrict__ btot) {
    __shared__ int s[CBLK];
    int k = blockIdx.x, t = threadIdx.x;
    int v = gcnt[t * CB + k];
    s[t] = v;
    __syncthreads();
    for (int off = 1; off < CBLK; off <<= 1) {
        int u = (t >= off) ? s[t - off] : 0;
        __syncthreads();
        s[t] += u;
        __syncthreads();
    }
    gcnt[t * CB + k] = s[t] - v;
    if (t == CBLK - 1) btot[k] = s[t];
}

// ---- Pass B2: scan bucket totals -> bstart ---------------------------------
__global__ void bucket_scan(const int* __restrict__ btot, int* __restrict__ bstart) {
    __shared__ int s[1024];
    int t = threadIdx.x;
    int v = (t < CB) ? btot[t] : 0;
    s[t] = v;
    __syncthreads();
    for (int off = 1; off < 1024; off <<= 1) {
        int u = (t >= off) ? s[t - off] : 0;
        __syncthreads();
        s[t] += u;
        __syncthreads();
    }
    if (t < CB) bstart[t] = s[t] - v;
    if (t == 0) bstart[CB] = N_EDGES;
}

// ---- Pass C: partition edges into coarse-bucket order (packed 4B) ----------
__global__ void partition_k(const int* __restrict__ src, const int* __restrict__ dst,
                            const int* __restrict__ gcnt, const int* __restrict__ bstart,
                            int* __restrict__ part) {
    __shared__ int base[CB];
    __shared__ int h[CB];
    int t = threadIdx.x, b = blockIdx.x;
    for (int i = t; i < CB; i += 256) {
        base[i] = bstart[i] + gcnt[b * CB + i];
        h[i] = 0;
    }
    __syncthreads();
    int i0 = b * EPB, i1 = min(i0 + EPB, NI4);
    for (int i = i0 + t; i < i1; i += 256) {
        int4 s4 = ((const int4*)src)[i];
        int4 d4 = ((const int4*)dst)[i];
        int k, r;
        k = d4.x >> 7; r = atomicAdd(&h[k], 1); part[base[k] + r] = s4.x | ((d4.x & 127) << 17);
        k = d4.y >> 7; r = atomicAdd(&h[k], 1); part[base[k] + r] = s4.y | ((d4.y & 127) << 17);
        k = d4.z >> 7; r = atomicAdd(&h[k], 1); part[base[k] + r] = s4.z | ((d4.z & 127) << 17);
        k = d4.w >> 7; r = atomicAdd(&h[k], 1); part[base[k] + r] = s4.w | ((d4.w & 127) << 17);
    }
}

// ---- Pass D FUSED with Layer 1: fine sort + ptr + LDS-staged gather + MLP --
// One block per 128-node bucket (782 blocks, ~50.7KB LDS -> 3 blocks/CU).
// Scatter phase stages each edge's 16B xb payload into LDS at its final slot,
// so the gather loop reads CONTIGUOUS LDS instead of an esrc->xb L2 chain.
// esrc is still written globally (gather2 consumes it). Fallback to the
// global path if a bucket exceeds STCAP edges (correctness for any dist).
__global__ void fine_gather1(const int* __restrict__ part, const int* __restrict__ bstart,
                             int* __restrict__ ptr, int* __restrict__ esrc,
                             const uint4* __restrict__ xb,
                             const float* __restrict__ x,
                             const float* __restrict__ w_rel1,
                             const float* __restrict__ b_rel1,
                             const float* __restrict__ w_root1,
                             unsigned short* __restrict__ h1,
                             unsigned char* __restrict__ h1f8) {
    __shared__ int fh[128];       // counts -> exclusive offsets (bucket-local)
    __shared__ int fo[128];       // scan workspace
    __shared__ int fr[128];       // scatter cursors
    __shared__ uint4 stage[STCAP];// 48 KB edge payloads in slot order
    int k = blockIdx.x, t = threadIdx.x;
    int e0 = bstart[k], e1 = bstart[k + 1];
    int ne = e1 - e0;
    bool useLds = (ne <= STCAP);
    if (t < 128) { fh[t] = 0; fr[t] = 0; }
    __syncthreads();
    for (int e = e0 + t; e < e1; e += 256)
        atomicAdd(&fh[(part[e] >> 17) & 127], 1);
    __syncthreads();
    int v = (t < 128) ? fh[t] : 0;
    if (t < 128) fo[t] = v;
    __syncthreads();
    for (int off = 1; off < 128; off <<= 1) {
        int u = (t >= off && t < 128) ? fo[t - off] : 0;
        __syncthreads();
        if (t < 128) fo[t] += u;
        __syncthreads();
    }
    if (t < 128) {
        int excl = fo[t] - v;
        int n_t = (k << 7) + t;
        if (n_t < N_NODES) ptr[n_t] = e0 + excl;
        fh[t] = excl;
    }
    __syncthreads();
    // scatter: esrc (global, for gather2) + xb payload into LDS stage
    for (int e = e0 + t; e < e1; e += 256) {
        int p = part[e];
        int d = (p >> 17) & 127;
        int s = p & 0x1FFFF;
        int r = atomicAdd(&fr[d], 1);
        int slot = fh[d] + r;
        esrc[e0 + slot] = s;
        if (useLds) stage[slot] = xb[s];
    }
    __syncthreads();   // slots + offsets complete

    // ---- layer-1 gather + transform (16-lane groups, LDS-resident edges) ---
    int ql = t & 15;
    int g  = t >> 4;   // 16 groups per block
    float wr[IN_DIM][4], wo[IN_DIM][4], bias[4];
#pragma unroll
    for (int j = 0; j < 4; ++j) {
        int ch = ql * 4 + j;
        bias[j] = b_rel1[ch];
#pragma unroll
        for (int kk = 0; kk < IN_DIM; ++kk) {
            wr[kk][j] = w_rel1[kk * HIDDEN + ch];
            wo[kk][j] = w_root1[kk * HIDDEN + ch];
        }
    }

    for (int nl = g; nl < 128; nl += 16) {
        int n = (k << 7) + nl;
        if (n >= N_NODES) break;
        int s0 = fh[nl];
        int s1 = (nl < 127) ? fh[nl + 1] : ne;
        float a[IN_DIM] = {0.f, 0.f, 0.f, 0.f, 0.f};
        if (useLds) {
            for (int i = s0 + ql; i < s1; i += 16) {
                uint4 p = stage[i];
                a[0] += blo(p.x); a[1] += bhi(p.x);
                a[2] += blo(p.y); a[3] += bhi(p.y);
                a[4] += blo(p.z);
            }
        } else {
            for (int i = s0 + ql; i < s1; i += 16) {
                uint4 p = xb[esrc[e0 + i]];
                a[0] += blo(p.x); a[1] += bhi(p.x);
                a[2] += blo(p.y); a[3] += bhi(p.y);
                a[4] += blo(p.z);
            }
        }
#pragma unroll
        for (int kk = 0; kk < IN_DIM; ++kk) {
            a[kk] += __shfl_xor(a[kk], 1, 64);
            a[kk] += __shfl_xor(a[kk], 2, 64);
            a[kk] += __shfl_xor(a[kk], 4, 64);
            a[kk] += __shfl_xor(a[kk], 8, 64);
        }
        float xr[IN_DIM];
#pragma unroll
        for (int kk = 0; kk < IN_DIM; ++kk) xr[kk] = x[(size_t)n * IN_DIM + kk];

        unsigned short hv[4];
        unsigned char  hf[4];
#pragma unroll
        for (int j = 0; j < 4; ++j) {
            float acc = bias[j];
#pragma unroll
            for (int kk = 0; kk < IN_DIM; ++kk)
                acc += a[kk] * wr[kk][j] + xr[kk] * wo[kk][j];
            float h = fmaxf(acc, 0.0f);
            hv[j] = f2bs(h);
            hf[j] = f2f8(h);
        }
        ushort4 v4; v4.x = hv[0]; v4.y = hv[1]; v4.z = hv[2]; v4.w = hv[3];
        *(ushort4*)(h1 + (size_t)n * HIDDEN + ql * 4) = v4;
        uchar4 c4; c4.x = hf[0]; c4.y = hf[1]; c4.z = hf[2]; c4.w = hf[3];
        *(uchar4*)(h1f8 + (size_t)n * HIDDEN + ql * 4) = c4;
    }
}

// ==================== GNN compute ===========================================

// ---- Layer 2: 16-lane-group fp8-row gather, 4-deep unroll, HW fp8 decode ---
__global__ void gather2_fp8(const unsigned* __restrict__ rows,   // row = 16 dwords
                            const int* __restrict__ ptr,
                            const int* __restrict__ esrc,
                            uint2* __restrict__ agg2) {          // row = 16 uint2
    int t    = threadIdx.x;
    int ql   = t & 15;
    int grp  = (blockIdx.x * blockDim.x + t) >> 4;
    int ngrp = (gridDim.x * blockDim.x) >> 4;

    for (int n = grp; n < N_NODES; n += ngrp) {
        int start = ptr[n], end = ptr[n + 1];
        float4 a0 = {0.f,0.f,0.f,0.f}, a1 = a0, a2 = a0, a3 = a0;
        int e = start;
        for (; e + 3 < end; e += 4) {
            int s0 = esrc[e], s1 = esrc[e + 1], s2 = esrc[e + 2], s3 = esrc[e + 3];
            unsigned r0 = rows[(size_t)s0 * 16 + ql];
            unsigned r1 = rows[(size_t)s1 * 16 + ql];
            unsigned r2 = rows[(size_t)s2 * 16 + ql];
            unsigned r3 = rows[(size_t)s3 * 16 + ql];
            acc8(a0, r0); acc8(a1, r1); acc8(a2, r2); acc8(a3, r3);
        }
        for (; e < end; ++e) {
            unsigned r0 = rows[(size_t)esrc[e] * 16 + ql];
            acc8(a0, r0);
        }
        float4 a;
        a.x = (a0.x + a1.x) + (a2.x + a3.x);
        a.y = (a0.y + a1.y) + (a2.y + a3.y);
        a.z = (a0.z + a1.z) + (a2.z + a3.z);
        a.w = (a0.w + a1.w) + (a2.w + a3.w);
        uint2 o;
        o.x = pack2(a.x, a.y);
        o.y = pack2(a.z, a.w);
        agg2[(size_t)n * 16 + ql] = o;   // 128B contiguous per node row
    }
}

// ---- Layer 2 transform via MFMA, FUSED with add-pool -----------------------
__global__ void mlp2_pool(const unsigned short* __restrict__ agg2,
                          const unsigned short* __restrict__ h1,
                          const float* __restrict__ w_rel2,
                          const float* __restrict__ b_rel2,
                          const float* __restrict__ w_root2,
                          const int* __restrict__ batch,
                          float* __restrict__ add_pool) {
    int lane = threadIdx.x & 63;
    int wv   = threadIdx.x >> 6;
    int row  = lane & 15;
    int quad = lane >> 4;
    int n    = wv * 16 + row;           // this lane's output column

    short8 bwr[2], bwo[2];
#pragma unroll
    for (int s = 0; s < 2; ++s)
#pragma unroll
        for (int j = 0; j < 8; ++j) {
            int k = 32 * s + quad * 8 + j;
            bwr[s][j] = (short)f2bs(w_rel2[k * HIDDEN + n]);
            bwo[s][j] = (short)f2bs(w_root2[k * HIDDEN + n]);
        }
    float bias = b_rel2[n];

    for (int t = blockIdx.x; t < M_TILES; t += gridDim.x) {
        int m0 = t * 16;
        size_t rbase = (size_t)(m0 + row) * HIDDEN;
        short8 aa0 = *(const short8*)(agg2 + rbase + quad * 8);
        short8 aa1 = *(const short8*)(agg2 + rbase + 32 + quad * 8);
        short8 ah0 = *(const short8*)(h1   + rbase + quad * 8);
        short8 ah1 = *(const short8*)(h1   + rbase + 32 + quad * 8);

        f32x4 acc = {bias, bias, bias, bias};
        acc = __builtin_amdgcn_mfma_f32_16x16x32_bf16(aa0, bwr[0], acc, 0, 0, 0);
        acc = __builtin_amdgcn_mfma_f32_16x16x32_bf16(aa1, bwr[1], acc, 0, 0, 0);
        acc = __builtin_amdgcn_mfma_f32_16x16x32_bf16(ah0, bwo[0], acc, 0, 0, 0);
        acc = __builtin_amdgcn_mfma_f32_16x16x32_bf16(ah1, bwo[1], acc, 0, 0, 0);

        float hv0 = fmaxf(acc[0], 0.0f), hv1 = fmaxf(acc[1], 0.0f);
        float hv2 = fmaxf(acc[2], 0.0f), hv3 = fmaxf(acc[3], 0.0f);

        int gLo = batch[m0], gHi = batch[m0 + 15];
        if (gLo == gHi) {
            float s = (hv0 + hv1) + (hv2 + hv3);
            s += __shfl_xor(s, 16, 64);
            s += __shfl_xor(s, 32, 64);
            if (quad == 0)
                atomicAdd(&add_pool[gLo * HIDDEN + n], s);
        } else {
            int m = m0 + quad * 4;
            atomicAdd(&add_pool[batch[m]     * HIDDEN + n], hv0);
            atomicAdd(&add_pool[batch[m + 1] * HIDDEN + n], hv1);
            atomicAdd(&add_pool[batch[m + 2] * HIDDEN + n], hv2);
            atomicAdd(&add_pool[batch[m + 3] * HIDDEN + n], hv3);
        }
    }
}

// ---- MLP head: one block (64 threads) per graph ----------------------------
__device__ __forceinline__ int lower_bound_i(const int* a, int n, int v) {
    int lo = 0, hi = n;
    while (lo < hi) { int mid = (lo + hi) >> 1; if (a[mid] < v) lo = mid + 1; else hi = mid; }
    return lo;
}

__global__ void head_mlp(const float* __restrict__ add_pool,
                         const int* __restrict__ batch,
                         const float* __restrict__ w_h1,
                         const float* __restrict__ b_h1,
                         const float* __restrict__ w_h2,
                         const float* __restrict__ b_h2,
                         float* __restrict__ out) {
    int g = blockIdx.x, t = threadIdx.x;

    __shared__ int s_cnt;
    if (t == 0) {
        int start = lower_bound_i(batch, N_NODES, g);
        int end   = lower_bound_i(batch, N_NODES, g + 1);
        s_cnt = end - start;
    }
    __syncthreads();
    float cnt = fmaxf((float)s_cnt, 1.0f);

    __shared__ float sg[2 * HIDDEN];
    float add = add_pool[(size_t)g * HIDDEN + t];
    sg[t]          = add / cnt;   // mean_pool
    sg[HIDDEN + t] = add;         // add_pool
    __syncthreads();

    float hid = b_h1[t];
#pragma unroll 16
    for (int i = 0; i < 2 * HIDDEN; ++i)
        hid += sg[i] * w_h1[i * HIDDEN + t];
    hid = fmaxf(hid, 0.0f);

    float res = hid * w_h2[t];
    for (int off = 32; off > 0; off >>= 1)
        res += __shfl_down(res, off, 64);
    if (t == 0) out[g] = res + b_h2[0];
}

extern "C" void kernel_launch(void* const* d_in, const int* in_sizes, int n_in,
                              void* d_out, int out_size, void* d_ws, size_t ws_size,
                              hipStream_t stream) {
    const float* x       = (const float*)d_in[0];
    const int*   ei      = (const int*)d_in[1];
    const int*   src     = ei;
    const int*   dst     = ei + N_EDGES;
    const int*   batch   = (const int*)d_in[2];
    const float* w_rel1  = (const float*)d_in[3];
    const float* b_rel1  = (const float*)d_in[4];
    const float* w_root1 = (const float*)d_in[5];
    const float* w_rel2  = (const float*)d_in[6];
    const float* b_rel2  = (const float*)d_in[7];
    const float* w_root2 = (const float*)d_in[8];
    const float* w_h1    = (const float*)d_in[9];
    const float* b_h1    = (const float*)d_in[10];
    const float* w_h2    = (const float*)d_in[11];
    const float* b_h2    = (const float*)d_in[12];
    float* out = (float*)d_out;

    int* base = (int*)d_ws;
    int*   gcnt     = base;                                   // CBLK*CB
    int*   btot     = gcnt + ((CBLK * CB + 3) & ~3);          // CB
    int*   bstart   = btot + ((CB + 3) & ~3);                 // CB+1
    float* add_pool = (float*)(bstart + ((CB + 1 + 3) & ~3)); // 128*64 f32
    int*   ptr      = (int*)(add_pool + NUM_GRAPHS * HIDDEN); // N+1
    int*   part     = ptr + ((N_NODES + 1 + 3) & ~3);         // E packed ints
    int*   esrc     = part + N_EDGES;                         // E
    unsigned short* h1   = (unsigned short*)(esrc + N_EDGES); // N*64 bf16
    unsigned short* agg2 = h1 + (size_t)N_NODES * HIDDEN;     // N*64 bf16
    unsigned char*  h1f8 = (unsigned char*)(agg2 + (size_t)N_NODES * HIDDEN); // N*64 fp8
    uint4*          xb   = (uint4*)(h1f8 + (size_t)N_NODES * HIDDEN);         // N*16B

    // ---- CSR build: two-level counting sort (write-locality by design) ----
    coarse_count<<<CBLK, 256, 0, stream>>>(dst, gcnt, x, xb, add_pool, ptr);
    block_scan<<<CB, CBLK, 0, stream>>>(gcnt, btot);
    bucket_scan<<<1, 1024, 0, stream>>>(btot, bstart);
    partition_k<<<CBLK, 256, 0, stream>>>(src, dst, gcnt, bstart, part);

    // ---- Fine sort + Layer 1 (fused; LDS-staged edge payloads) ----
    fine_gather1<<<CB, 256, 0, stream>>>(part, bstart, ptr, esrc, xb, x,
                                         w_rel1, b_rel1, w_root1, h1, h1f8);
    // ---- Layer 2 gather (16-lane groups, 4-deep unroll, HW fp8 decode) ----
    gather2_fp8<<<2048, 256, 0, stream>>>((const unsigned*)h1f8, ptr, esrc, (uint2*)agg2);
    // ---- Layer 2 transform (MFMA) + add-pool ----
    mlp2_pool<<<2048, 256, 0, stream>>>(agg2, h1, w_rel2, b_rel2, w_root2, batch, add_pool);
    // ---- Head ----
    head_mlp<<<NUM_GRAPHS, 64, 0, stream>>>(add_pool, batch, w_h1, b_h1, w_h2, b_h2, out);
}

// Round 9
// 190.266 us; speedup vs baseline: 1.9487x; 1.0271x over previous
//
#include <hip/hip_runtime.h>
#include <hip/hip_bf16.h>

#define N_NODES    100000
#define N_EDGES    1200000
#define NUM_GRAPHS 128
#define IN_DIM     5
#define HIDDEN     64
#define M_TILES    (N_NODES / 16)   // 6250 (exact; 6250*16 == N_NODES)
#define NI4        (N_EDGES / 4)    // 300000 int4 groups

#define CB    782                   // coarse buckets of 128 nodes: ceil(N/128)
#define CBLK  256                   // partition blocks
#define EPB   ((NI4 + CBLK - 1) / CBLK)   // 1172 int4-groups per block
#define STCAP 3072                  // LDS edge-payload capacity (avg 1534/bucket)
#define AGP   72                    // LDS gathered-tile row stride (halfwords)

typedef __attribute__((ext_vector_type(8))) short short8;   // 8 bf16 (4 VGPRs)
typedef __attribute__((ext_vector_type(4))) float f32x4;
typedef __attribute__((ext_vector_type(2))) float f32x2;

#if defined(__has_builtin)
#if __has_builtin(__builtin_amdgcn_cvt_pk_f32_fp8)
#define HAS_HWF8 1
#endif
#endif

// fp32 -> bf16 bits (RNE)
__device__ __forceinline__ unsigned short f2bs(float f) {
    union { float f; unsigned u; } v; v.f = f;
    return (unsigned short)((v.u + 0x7FFFu + ((v.u >> 16) & 1u)) >> 16);
}
// bf16 bits -> fp32
__device__ __forceinline__ float bs2f(unsigned short s) {
    union { unsigned u; float f; } v; v.u = ((unsigned)s) << 16;
    return v.f;
}
__device__ __forceinline__ float blo(unsigned p) { return bs2f((unsigned short)(p & 0xffff)); }
__device__ __forceinline__ float bhi(unsigned p) { return bs2f((unsigned short)(p >> 16)); }
__device__ __forceinline__ unsigned pack2(float a, float b) {
    return ((unsigned)f2bs(b) << 16) | (unsigned)f2bs(a);
}

// fp32 (>=0) -> fp8 e4m3 bits (OCP), RNE, denorm-exact (magic-multiply trick)
__device__ __forceinline__ unsigned char f2f8(float f) {
    union { float f; unsigned u; } v; v.f = f * 0x1p-120f;
    unsigned u = v.u + 0x7FFFFu + ((v.u >> 20) & 1u);
    return (unsigned char)(u >> 20);
}
// fp8 e4m3 bits -> fp32 (exact inverse)
__device__ __forceinline__ float f82f(unsigned b) {
    union { unsigned u; float f; } v; v.u = (b & 0x7Fu) << 20;
    return v.f * 0x1p120f;
}

// accumulate 4 fp8 bytes of r into a (HW decode when available; bit-identical)
__device__ __forceinline__ void acc8(float4& a, unsigned r) {
#ifdef HAS_HWF8
    f32x2 lo = __builtin_amdgcn_cvt_pk_f32_fp8((int)r, false);
    f32x2 hi = __builtin_amdgcn_cvt_pk_f32_fp8((int)r, true);
    a.x += lo[0]; a.y += lo[1]; a.z += hi[0]; a.w += hi[1];
#else
    a.x += f82f(r); a.y += f82f(r >> 8); a.z += f82f(r >> 16); a.w += f82f(r >> 24);
#endif
}

// ==================== CSR build: two-level counting sort ====================
// part entries are PACKED 4B: src (bits 0..16) | (dst & 127) << 17.
// Ledger: no grid.sync (r6: ~45us each); no per-block column-sum self-scan
// (r7: latency-bound, 65us). Scanning btot alone (782 ints) per block is ~1us
// and removes the bucket_scan dispatch.

// ---- Pass A: coarse histogram (dst>>7, LDS) + xb pack + misc init ----------
__global__ void coarse_count(const int* __restrict__ dst, int* __restrict__ gcnt,
                             const float* __restrict__ x, uint4* __restrict__ xb,
                             float* __restrict__ add_pool, int* __restrict__ ptr) {
    __shared__ int h[CB];
    int t = threadIdx.x, b = blockIdx.x;
    for (int i = t; i < CB; i += 256) h[i] = 0;
    __syncthreads();
    int i0 = b * EPB, i1 = min(i0 + EPB, NI4);
    for (int i = i0 + t; i < i1; i += 256) {
        int4 d = ((const int4*)dst)[i];
        atomicAdd(&h[d.x >> 7], 1);
        atomicAdd(&h[d.y >> 7], 1);
        atomicAdd(&h[d.z >> 7], 1);
        atomicAdd(&h[d.w >> 7], 1);
    }
    __syncthreads();
    for (int i = t; i < CB; i += 256) gcnt[b * CB + i] = h[i];

    // fold: pack x rows into 16B (5 bf16 + pad) for the layer-1 edge gather
    for (int n = b * 256 + t; n < N_NODES; n += CBLK * 256) {
        const float* xr = x + (size_t)n * IN_DIM;
        uint4 o;
        o.x = pack2(xr[0], xr[1]);
        o.y = pack2(xr[2], xr[3]);
        o.z = pack2(xr[4], 0.0f);
        o.w = 0u;
        xb[n] = o;
    }
    // fold: zero add_pool, terminate ptr
    if (b == 0) {
        for (int i = t; i < NUM_GRAPHS * HIDDEN; i += 256) add_pool[i] = 0.0f;
        if (t == 0) ptr[N_NODES] = N_EDGES;
    }
}

// ---- Pass B: per-bucket exclusive scan over the 256 partition blocks -------
__global__ void block_scan(int* __restrict__ gcnt, int* __restrict__ btot) {
    __shared__ int s[CBLK];
    int k = blockIdx.x, t = threadIdx.x;
    int v = gcnt[t * CB + k];
    s[t] = v;
    __syncthreads();
    for (int off = 1; off < CBLK; off <<= 1) {
        int u = (t >= off) ? s[t - off] : 0;
        __syncthreads();
        s[t] += u;
        __syncthreads();
    }
    gcnt[t * CB + k] = s[t] - v;
    if (t == CBLK - 1) btot[k] = s[t];
}

// ---- Pass C: partition; bstart recomputed locally from btot (cheap) --------
__global__ void partition_k(const int* __restrict__ src, const int* __restrict__ dst,
                            const int* __restrict__ gcnt, const int* __restrict__ btot,
                            int* __restrict__ bstart, int* __restrict__ part) {
    __shared__ int sb[CB];    // btot -> exclusive bucket starts
    __shared__ int base[CB];  // this block's write cursors base
    __shared__ int h[CB];     // scatter cursors
    int t = threadIdx.x, b = blockIdx.x;
    for (int i = t; i < CB; i += 256) sb[i] = btot[i];
    __syncthreads();
    // exclusive scan of sb by wave 0 (13 entries/lane + shuffle scan)
    if (t < 64) {
        int loc[13];                      // 64*13 = 832 >= CB
        int base_i = t * 13;
        int sum = 0;
#pragma unroll
        for (int j = 0; j < 13; ++j) {
            int idx = base_i + j;
            int c = (idx < CB) ? sb[idx] : 0;
            loc[j] = sum; sum += c;
        }
        int inc = sum;
#pragma unroll
        for (int off = 1; off < 64; off <<= 1) {
            int u = __shfl_up(inc, off, 64);
            if (t >= off) inc += u;
        }
        int excl = inc - sum;
#pragma unroll
        for (int j = 0; j < 13; ++j) {
            int idx = base_i + j;
            if (idx < CB) sb[idx] = excl + loc[j];
        }
    }
    __syncthreads();
    for (int i = t; i < CB; i += 256) {
        int bs = sb[i];
        base[i] = bs + gcnt[b * CB + i];
        h[i] = 0;
        if (b == 0) bstart[i] = bs;     // publish for fine_gather1
    }
    if (b == 0 && t == 0) bstart[CB] = N_EDGES;
    __syncthreads();
    int i0 = b * EPB, i1 = min(i0 + EPB, NI4);
    for (int i = i0 + t; i < i1; i += 256) {
        int4 s4 = ((const int4*)src)[i];
        int4 d4 = ((const int4*)dst)[i];
        int k, r;
        k = d4.x >> 7; r = atomicAdd(&h[k], 1); part[base[k] + r] = s4.x | ((d4.x & 127) << 17);
        k = d4.y >> 7; r = atomicAdd(&h[k], 1); part[base[k] + r] = s4.y | ((d4.y & 127) << 17);
        k = d4.z >> 7; r = atomicAdd(&h[k], 1); part[base[k] + r] = s4.z | ((d4.z & 127) << 17);
        k = d4.w >> 7; r = atomicAdd(&h[k], 1); part[base[k] + r] = s4.w | ((d4.w & 127) << 17);
    }
}

// ---- Pass D FUSED with Layer 1: fine sort + ptr + LDS-staged gather + MLP --
__global__ void fine_gather1(const int* __restrict__ part, const int* __restrict__ bstart,
                             int* __restrict__ ptr, int* __restrict__ esrc,
                             const uint4* __restrict__ xb,
                             const float* __restrict__ x,
                             const float* __restrict__ w_rel1,
                             const float* __restrict__ b_rel1,
                             const float* __restrict__ w_root1,
                             unsigned short* __restrict__ h1,
                             unsigned char* __restrict__ h1f8) {
    __shared__ int fh[128];       // counts -> exclusive offsets (bucket-local)
    __shared__ int fo[128];       // scan workspace
    __shared__ int fr[128];       // scatter cursors
    __shared__ uint4 stage[STCAP];// 48 KB edge payloads in slot order
    int k = blockIdx.x, t = threadIdx.x;
    int e0 = bstart[k], e1 = bstart[k + 1];
    int ne = e1 - e0;
    bool useLds = (ne <= STCAP);
    if (t < 128) { fh[t] = 0; fr[t] = 0; }
    __syncthreads();
    for (int e = e0 + t; e < e1; e += 256)
        atomicAdd(&fh[(part[e] >> 17) & 127], 1);
    __syncthreads();
    int v = (t < 128) ? fh[t] : 0;
    if (t < 128) fo[t] = v;
    __syncthreads();
    for (int off = 1; off < 128; off <<= 1) {
        int u = (t >= off && t < 128) ? fo[t - off] : 0;
        __syncthreads();
        if (t < 128) fo[t] += u;
        __syncthreads();
    }
    if (t < 128) {
        int excl = fo[t] - v;
        int n_t = (k << 7) + t;
        if (n_t < N_NODES) ptr[n_t] = e0 + excl;
        fh[t] = excl;
    }
    __syncthreads();
    for (int e = e0 + t; e < e1; e += 256) {
        int p = part[e];
        int d = (p >> 17) & 127;
        int s = p & 0x1FFFF;
        int r = atomicAdd(&fr[d], 1);
        int slot = fh[d] + r;
        esrc[e0 + slot] = s;
        if (useLds) stage[slot] = xb[s];
    }
    __syncthreads();

    int ql = t & 15;
    int g  = t >> 4;
    float wr[IN_DIM][4], wo[IN_DIM][4], bias[4];
#pragma unroll
    for (int j = 0; j < 4; ++j) {
        int ch = ql * 4 + j;
        bias[j] = b_rel1[ch];
#pragma unroll
        for (int kk = 0; kk < IN_DIM; ++kk) {
            wr[kk][j] = w_rel1[kk * HIDDEN + ch];
            wo[kk][j] = w_root1[kk * HIDDEN + ch];
        }
    }

    for (int nl = g; nl < 128; nl += 16) {
        int n = (k << 7) + nl;
        if (n >= N_NODES) break;
        int s0 = fh[nl];
        int s1 = (nl < 127) ? fh[nl + 1] : ne;
        float a[IN_DIM] = {0.f, 0.f, 0.f, 0.f, 0.f};
        if (useLds) {
            for (int i = s0 + ql; i < s1; i += 16) {
                uint4 p = stage[i];
                a[0] += blo(p.x); a[1] += bhi(p.x);
                a[2] += blo(p.y); a[3] += bhi(p.y);
                a[4] += blo(p.z);
            }
        } else {
            for (int i = s0 + ql; i < s1; i += 16) {
                uint4 p = xb[esrc[e0 + i]];
                a[0] += blo(p.x); a[1] += bhi(p.x);
                a[2] += blo(p.y); a[3] += bhi(p.y);
                a[4] += blo(p.z);
            }
        }
#pragma unroll
        for (int kk = 0; kk < IN_DIM; ++kk) {
            a[kk] += __shfl_xor(a[kk], 1, 64);
            a[kk] += __shfl_xor(a[kk], 2, 64);
            a[kk] += __shfl_xor(a[kk], 4, 64);
            a[kk] += __shfl_xor(a[kk], 8, 64);
        }
        float xr[IN_DIM];
#pragma unroll
        for (int kk = 0; kk < IN_DIM; ++kk) xr[kk] = x[(size_t)n * IN_DIM + kk];

        unsigned short hv[4];
        unsigned char  hf[4];
#pragma unroll
        for (int j = 0; j < 4; ++j) {
            float acc = bias[j];
#pragma unroll
            for (int kk = 0; kk < IN_DIM; ++kk)
                acc += a[kk] * wr[kk][j] + xr[kk] * wo[kk][j];
            float h = fmaxf(acc, 0.0f);
            hv[j] = f2bs(h);
            hf[j] = f2f8(h);
        }
        ushort4 v4; v4.x = hv[0]; v4.y = hv[1]; v4.z = hv[2]; v4.w = hv[3];
        *(ushort4*)(h1 + (size_t)n * HIDDEN + ql * 4) = v4;
        uchar4 c4; c4.x = hf[0]; c4.y = hf[1]; c4.z = hf[2]; c4.w = hf[3];
        *(uchar4*)(h1f8 + (size_t)n * HIDDEN + ql * 4) = c4;
    }
}

// ==================== Layer 2: gather + MFMA transform + pool, FUSED ========
// Per 16-node tile: 16 groups x 16 lanes gather all 16 fp8 rows in parallel
// (lane ql owns dword ql), pack bf16 into a padded LDS tile, then the 4 waves
// run the MFMA transform + add-pool on it. agg2 never touches global memory.
__global__ void gather2_mlp2(const unsigned* __restrict__ rows,   // fp8 row = 16 dwords
                             const int* __restrict__ ptr,
                             const int* __restrict__ esrc,
                             const unsigned short* __restrict__ h1,
                             const float* __restrict__ w_rel2,
                             const float* __restrict__ b_rel2,
                             const float* __restrict__ w_root2,
                             const int* __restrict__ batch,
                             float* __restrict__ add_pool) {
    __shared__ unsigned short ag[16 * AGP];   // gathered tile, bf16, pad 72
    int tid  = threadIdx.x;
    int lane = tid & 63, wv = tid >> 6;
    int row  = lane & 15, quad = lane >> 4;
    int n    = wv * 16 + row;                 // this lane's output column
    int g    = tid >> 4, ql = tid & 15;       // gather roles

    short8 bwr[2], bwo[2];
#pragma unroll
    for (int s = 0; s < 2; ++s)
#pragma unroll
        for (int j = 0; j < 8; ++j) {
            int k = 32 * s + quad * 8 + j;
            bwr[s][j] = (short)f2bs(w_rel2[k * HIDDEN + n]);
            bwo[s][j] = (short)f2bs(w_root2[k * HIDDEN + n]);
        }
    float bias = b_rel2[n];

    for (int t = blockIdx.x; t < M_TILES; t += gridDim.x) {
        int m0 = t * 16;
        // ---- gather phase: group g gathers node m0+g ----
        int nd = m0 + g;
        int start = ptr[nd], end = ptr[nd + 1];
        float4 a0 = {0.f, 0.f, 0.f, 0.f}, a1 = a0;
        int e = start;
        for (; e + 1 < end; e += 2) {
            int sA = esrc[e], sB = esrc[e + 1];
            unsigned r0 = rows[(size_t)sA * 16 + ql];
            unsigned r1 = rows[(size_t)sB * 16 + ql];
            acc8(a0, r0); acc8(a1, r1);
        }
        if (e < end) {
            unsigned r0 = rows[(size_t)esrc[e] * 16 + ql];
            acc8(a0, r0);
        }
        a0.x += a1.x; a0.y += a1.y; a0.z += a1.z; a0.w += a1.w;
        uint2 pk;
        pk.x = pack2(a0.x, a0.y);
        pk.y = pack2(a0.z, a0.w);
        *(uint2*)&ag[g * AGP + ql * 4] = pk;
        __syncthreads();

        // ---- MFMA transform + pool (all 4 waves, same tile) ----
        size_t rbase = (size_t)(m0 + row) * HIDDEN;
        short8 aa0 = *(const short8*)&ag[row * AGP + quad * 8];
        short8 aa1 = *(const short8*)&ag[row * AGP + 32 + quad * 8];
        short8 ah0 = *(const short8*)(h1 + rbase + quad * 8);
        short8 ah1 = *(const short8*)(h1 + rbase + 32 + quad * 8);

        f32x4 acc = {bias, bias, bias, bias};
        acc = __builtin_amdgcn_mfma_f32_16x16x32_bf16(aa0, bwr[0], acc, 0, 0, 0);
        acc = __builtin_amdgcn_mfma_f32_16x16x32_bf16(aa1, bwr[1], acc, 0, 0, 0);
        acc = __builtin_amdgcn_mfma_f32_16x16x32_bf16(ah0, bwo[0], acc, 0, 0, 0);
        acc = __builtin_amdgcn_mfma_f32_16x16x32_bf16(ah1, bwo[1], acc, 0, 0, 0);

        float hv0 = fmaxf(acc[0], 0.0f), hv1 = fmaxf(acc[1], 0.0f);
        float hv2 = fmaxf(acc[2], 0.0f), hv3 = fmaxf(acc[3], 0.0f);

        int gLo = batch[m0], gHi = batch[m0 + 15];
        if (gLo == gHi) {
            float s = (hv0 + hv1) + (hv2 + hv3);
            s += __shfl_xor(s, 16, 64);
            s += __shfl_xor(s, 32, 64);
            if (quad == 0)
                atomicAdd(&add_pool[gLo * HIDDEN + n], s);
        } else {
            int m = m0 + quad * 4;
            atomicAdd(&add_pool[batch[m]     * HIDDEN + n], hv0);
            atomicAdd(&add_pool[batch[m + 1] * HIDDEN + n], hv1);
            atomicAdd(&add_pool[batch[m + 2] * HIDDEN + n], hv2);
            atomicAdd(&add_pool[batch[m + 3] * HIDDEN + n], hv3);
        }
        __syncthreads();   // protect ag before next tile's gather overwrites
    }
}

// ---- MLP head: one block (64 threads) per graph ----------------------------
__device__ __forceinline__ int lower_bound_i(const int* a, int n, int v) {
    int lo = 0, hi = n;
    while (lo < hi) { int mid = (lo + hi) >> 1; if (a[mid] < v) lo = mid + 1; else hi = mid; }
    return lo;
}

__global__ void head_mlp(const float* __restrict__ add_pool,
                         const int* __restrict__ batch,
                         const float* __restrict__ w_h1,
                         const float* __restrict__ b_h1,
                         const float* __restrict__ w_h2,
                         const float* __restrict__ b_h2,
                         float* __restrict__ out) {
    int g = blockIdx.x, t = threadIdx.x;

    __shared__ int s_cnt;
    if (t == 0) {
        int start = lower_bound_i(batch, N_NODES, g);
        int end   = lower_bound_i(batch, N_NODES, g + 1);
        s_cnt = end - start;
    }
    __syncthreads();
    float cnt = fmaxf((float)s_cnt, 1.0f);

    __shared__ float sg[2 * HIDDEN];
    float add = add_pool[(size_t)g * HIDDEN + t];
    sg[t]          = add / cnt;   // mean_pool
    sg[HIDDEN + t] = add;         // add_pool
    __syncthreads();

    float hid = b_h1[t];
#pragma unroll 16
    for (int i = 0; i < 2 * HIDDEN; ++i)
        hid += sg[i] * w_h1[i * HIDDEN + t];
    hid = fmaxf(hid, 0.0f);

    float res = hid * w_h2[t];
    for (int off = 32; off > 0; off >>= 1)
        res += __shfl_down(res, off, 64);
    if (t == 0) out[g] = res + b_h2[0];
}

extern "C" void kernel_launch(void* const* d_in, const int* in_sizes, int n_in,
                              void* d_out, int out_size, void* d_ws, size_t ws_size,
                              hipStream_t stream) {
    const float* x       = (const float*)d_in[0];
    const int*   ei      = (const int*)d_in[1];
    const int*   src     = ei;
    const int*   dst     = ei + N_EDGES;
    const int*   batch   = (const int*)d_in[2];
    const float* w_rel1  = (const float*)d_in[3];
    const float* b_rel1  = (const float*)d_in[4];
    const float* w_root1 = (const float*)d_in[5];
    const float* w_rel2  = (const float*)d_in[6];
    const float* b_rel2  = (const float*)d_in[7];
    const float* w_root2 = (const float*)d_in[8];
    const float* w_h1    = (const float*)d_in[9];
    const float* b_h1    = (const float*)d_in[10];
    const float* w_h2    = (const float*)d_in[11];
    const float* b_h2    = (const float*)d_in[12];
    float* out = (float*)d_out;

    int* base = (int*)d_ws;
    int*   gcnt     = base;                                   // CBLK*CB
    int*   btot     = gcnt + ((CBLK * CB + 3) & ~3);          // CB
    int*   bstart   = btot + ((CB + 3) & ~3);                 // CB+1
    float* add_pool = (float*)(bstart + ((CB + 1 + 3) & ~3)); // 128*64 f32
    int*   ptr      = (int*)(add_pool + NUM_GRAPHS * HIDDEN); // N+1
    int*   part     = ptr + ((N_NODES + 1 + 3) & ~3);         // E packed ints
    int*   esrc     = part + N_EDGES;                         // E
    unsigned short* h1   = (unsigned short*)(esrc + N_EDGES); // N*64 bf16
    unsigned char*  h1f8 = (unsigned char*)(h1 + (size_t)N_NODES * HIDDEN);   // N*64 fp8
    uint4*          xb   = (uint4*)(h1f8 + (size_t)N_NODES * HIDDEN);         // N*16B

    // ---- CSR build: 3 dispatches (bucket_scan folded into partition_k) ----
    coarse_count<<<CBLK, 256, 0, stream>>>(dst, gcnt, x, xb, add_pool, ptr);
    block_scan<<<CB, CBLK, 0, stream>>>(gcnt, btot);
    partition_k<<<CBLK, 256, 0, stream>>>(src, dst, gcnt, btot, bstart, part);

    // ---- Fine sort + Layer 1 (fused; LDS-staged edge payloads) ----
    fine_gather1<<<CB, 256, 0, stream>>>(part, bstart, ptr, esrc, xb, x,
                                         w_rel1, b_rel1, w_root1, h1, h1f8);
    // ---- Layer 2: gather + MFMA transform + pool, all in one kernel ----
    gather2_mlp2<<<2048, 256, 0, stream>>>((const unsigned*)h1f8, ptr, esrc, h1,
                                           w_rel2, b_rel2, w_root2, batch, add_pool);
    // ---- Head ----
    head_mlp<<<NUM_GRAPHS, 64, 0, stream>>>(add_pool, batch, w_h1, b_h1, w_h2, b_h2, out);
}